// Round 1
// baseline (134.841 us; speedup 1.0000x reference)
//
#include <hip/hip_runtime.h>
#include <math.h>

#define BS 16
#define NPTS 2048
#define MPTS 2048
#define KSEG 32
#define DDIM 128

// ws float layout
#define ACC_TOTAL 0
#define ACC_COUNT 1
#define OFF_SUPP 16
#define OFF_SUPF (16 + BS*KSEG)          // 528
#define OFF_S2D  (16 + 2*BS*KSEG)        // 1040
#define OFF_CHAM 2048                    // bs*N floats
#define WS_FLOATS (OFF_CHAM + BS*NPTS)

__global__ __launch_bounds__(256) void init_ws_kernel(float* ws) {
    // zero the accumulator region [0, OFF_CHAM)
    for (int i = threadIdx.x; i < OFF_CHAM; i += 256) ws[i] = 0.0f;
}

__device__ inline void compute_xform(
    const float* __restrict__ p_rot, const float* __restrict__ p_t,
    const float* __restrict__ f_rot, const float* __restrict__ f_t,
    const float* __restrict__ tg_rot, const float* __restrict__ tg_t,
    const float* __restrict__ sr_rot, const float* __restrict__ sr_t,
    int b, float R[3][3], float tv[3])
{
    float P[9], F[9], Tg[9], Sr[9];
#pragma unroll
    for (int i = 0; i < 9; i++) {
        P[i]  = p_rot[b*9+i];  F[i]  = f_rot[b*9+i];
        Tg[i] = tg_rot[b*9+i]; Sr[i] = sr_rot[b*9+i];
    }
    float pt[3], ft[3], tt[3], st[3];
#pragma unroll
    for (int i = 0; i < 3; i++) {
        pt[i] = p_t[b*3+i]; ft[i] = f_t[b*3+i];
        tt[i] = tg_t[b*3+i]; st[i] = sr_t[b*3+i];
    }
    // A = P @ Tg^T ; B = A @ Sr ; R = B @ F^T   (row-vector convention)
    float A[9], B[9];
#pragma unroll
    for (int i = 0; i < 3; i++)
#pragma unroll
        for (int j = 0; j < 3; j++)
            A[i*3+j] = P[i*3+0]*Tg[j*3+0] + P[i*3+1]*Tg[j*3+1] + P[i*3+2]*Tg[j*3+2];
#pragma unroll
    for (int i = 0; i < 3; i++)
#pragma unroll
        for (int j = 0; j < 3; j++)
            B[i*3+j] = A[i*3+0]*Sr[0*3+j] + A[i*3+1]*Sr[1*3+j] + A[i*3+2]*Sr[2*3+j];
#pragma unroll
    for (int i = 0; i < 3; i++)
#pragma unroll
        for (int j = 0; j < 3; j++)
            R[i][j] = B[i*3+0]*F[j*3+0] + B[i*3+1]*F[j*3+1] + B[i*3+2]*F[j*3+2];
    // t = (((p_t - tg_t) @ Tg^T) @ Sr + sr_t - f_t) @ F^T
    float t0[3], t1[3], t2[3], t3[3];
#pragma unroll
    for (int i = 0; i < 3; i++) t0[i] = pt[i] - tt[i];
#pragma unroll
    for (int j = 0; j < 3; j++)
        t1[j] = t0[0]*Tg[j*3+0] + t0[1]*Tg[j*3+1] + t0[2]*Tg[j*3+2];
#pragma unroll
    for (int j = 0; j < 3; j++)
        t2[j] = t1[0]*Sr[0*3+j] + t1[1]*Sr[1*3+j] + t1[2]*Sr[2*3+j];
#pragma unroll
    for (int i = 0; i < 3; i++) t3[i] = t2[i] + st[i] - ft[i];
#pragma unroll
    for (int j = 0; j < 3; j++)
        tv[j] = t3[0]*F[j*3+0] + t3[1]*F[j*3+1] + t3[2]*F[j*3+2];
}

// grid: BS * 32 blocks; block handles 64 points n, 4 threads per point split M.
__global__ __launch_bounds__(256) void cham_kernel(
    const float* __restrict__ pc_partial, const float* __restrict__ deformed,
    const float* __restrict__ p_rot, const float* __restrict__ p_t,
    const float* __restrict__ f_rot, const float* __restrict__ f_t,
    const float* __restrict__ tg_rot, const float* __restrict__ tg_t,
    const float* __restrict__ sr_rot, const float* __restrict__ sr_t,
    float* __restrict__ cham)
{
    __shared__ float4 ydat[MPTS];     // 32 KB
    __shared__ float redbuf[256];

    const int b = blockIdx.x >> 5;
    const int chunk = blockIdx.x & 31;
    const int t = threadIdx.x;

    // stage deformed: [b][3][M] -> float4 {y0,y1,y2,|y|^2}
    const float* def0 = deformed + (size_t)b * 3 * MPTS;
    for (int m = t; m < MPTS; m += 256) {
        float y0 = def0[m], y1 = def0[MPTS + m], y2 = def0[2*MPTS + m];
        ydat[m] = make_float4(y0, y1, y2, y0*y0 + y1*y1 + y2*y2);
    }

    float R[3][3], tv[3];
    compute_xform(p_rot, p_t, f_rot, f_t, tg_rot, tg_t, sr_rot, sr_t, b, R, tv);

    __syncthreads();

    const int nl = t & 63;
    const int q  = t >> 6;          // quarter of M
    const int n  = chunk * 64 + nl;

    const float* pc = pc_partial + ((size_t)b * NPTS + n) * 3;
    const float px = pc[0], py = pc[1], pz = pc[2];
    const float x0 = px*R[0][0] + py*R[1][0] + pz*R[2][0] + tv[0];
    const float x1 = px*R[0][1] + py*R[1][1] + pz*R[2][1] + tv[1];
    const float x2 = px*R[0][2] + py*R[1][2] + pz*R[2][2] + tv[2];
    const float xn = x0*x0 + x1*x1 + x2*x2;

    float mn = 3.402823466e+38f;
    const int m0 = q * (MPTS/4);
#pragma unroll 4
    for (int m = m0; m < m0 + MPTS/4; m++) {
        float4 y = ydat[m];                       // broadcast read
        float dot = x0*y.x + x1*y.y + x2*y.z;
        float d2 = xn + y.w - 2.0f*dot;
        mn = fminf(mn, d2);
    }

    redbuf[t] = mn;
    __syncthreads();
    if (t < 64) {
        float v = fminf(fminf(redbuf[t], redbuf[t+64]),
                        fminf(redbuf[t+128], redbuf[t+192]));
        cham[(size_t)b * NPTS + chunk * 64 + t] = fmaxf(v, 0.0f);
    }
}

// grid: BS * 8 blocks; block handles 256 n rows, all K=32 segments.
__global__ __launch_bounds__(256) void seg_kernel(
    const float* __restrict__ seg_p, const float* __restrict__ seg_f,
    float* __restrict__ ws)
{
    __shared__ float chamLDS[256];
    __shared__ float red[3][256];

    const int b = blockIdx.x >> 3;
    const int nc = blockIdx.x & 7;
    const int t = threadIdx.x;
    const int n0 = nc * 256;

    chamLDS[t] = ws[OFF_CHAM + (size_t)b * NPTS + n0 + t];
    __syncthreads();

    const int k  = t & 31;
    const int ng = t >> 5;   // 8 n-groups
    const float* sp = seg_p + ((size_t)b * NPTS + n0) * KSEG;
    const float* sf = seg_f + ((size_t)b * NPTS + n0) * KSEG;

    float ap = 0.f, af = 0.f, a2 = 0.f;
#pragma unroll 4
    for (int i = 0; i < 32; i++) {
        int n = ng + 8 * i;
        float c  = chamLDS[n];
        float vp = sp[n * KSEG + k];
        float vf = sf[n * KSEG + k];
        ap += vp;
        a2 += vp * c;
        af += vf;
    }
    red[0][t] = ap; red[1][t] = af; red[2][t] = a2;
    __syncthreads();
    if (t < KSEG) {
        float s0 = 0.f, s1 = 0.f, s2 = 0.f;
#pragma unroll
        for (int g = 0; g < 8; g++) {
            s0 += red[0][g*32 + t];
            s1 += red[1][g*32 + t];
            s2 += red[2][g*32 + t];
        }
        atomicAdd(&ws[OFF_SUPP + b*KSEG + t], s0);
        atomicAdd(&ws[OFF_SUPF + b*KSEG + t], s1);
        atomicAdd(&ws[OFF_S2D  + b*KSEG + t], s2);
    }
}

// grid: BS*2 blocks; block handles 16 (b,k) cells, 16 threads per cell over D.
__global__ __launch_bounds__(256) void loss_kernel(
    const float* __restrict__ rf_tok, const float* __restrict__ rp_tok,
    float* __restrict__ ws)
{
    const int b  = blockIdx.x >> 1;
    const int kh = blockIdx.x & 1;
    const int t = threadIdx.x;
    const int cell = t >> 4;   // 0..15
    const int dg   = t & 15;
    const int k = kh * 16 + cell;

    const float supp = ws[OFF_SUPP + b*KSEG + k];
    const float supf = ws[OFF_SUPF + b*KSEG + k];
    const float s2d  = ws[OFF_S2D  + b*KSEG + k];
    const float spv = fmaxf(supp, 1.0f);
    const float sfv = fmaxf(supf, 1.0f);

    const float* rf = rf_tok + ((size_t)b * KSEG + k) * DDIM;
    const float* rp = rp_tok + ((size_t)b * KSEG + k) * DDIM;
    float acc = 0.f;
#pragma unroll
    for (int j = 0; j < 8; j++) {
        int d = dg + 16 * j;
        float v = rf[d] / sfv - rp[d] / spv;
        acc += v * v;
    }
#pragma unroll
    for (int off = 8; off; off >>= 1) acc += __shfl_xor(acc, off);

    __shared__ float lbuf[16], cbuf[16];
    if (dg == 0) {
        bool valid = (supp >= 20.0f) && (supf >= 20.0f);
        float arg = s2d / spv / 0.05f;
        float rel = 1.0f / (1.0f + expf(-arg));
        float ld = acc - rel; ld = ld * ld;
        bool msk = valid && (ld <= 20.0f);
        lbuf[cell] = msk ? ld : 0.0f;
        cbuf[cell] = msk ? 1.0f : 0.0f;
    }
    __syncthreads();
    if (t == 0) {
        float st = 0.f, sc = 0.f;
#pragma unroll
        for (int i = 0; i < 16; i++) { st += lbuf[i]; sc += cbuf[i]; }
        atomicAdd(&ws[ACC_TOTAL], st);
        atomicAdd(&ws[ACC_COUNT], sc);
    }
}

__global__ void final_kernel(const float* __restrict__ ws, float* __restrict__ out) {
    out[0] = ws[ACC_TOTAL] / (ws[ACC_COUNT] + 1.0f) * 1.0f;  // WEIGHT = 1.0
}

extern "C" void kernel_launch(void* const* d_in, const int* in_sizes, int n_in,
                              void* d_out, int out_size, void* d_ws, size_t ws_size,
                              hipStream_t stream) {
    const float* r_tokens_full    = (const float*)d_in[0];
    const float* r_tokens_partial = (const float*)d_in[1];
    const float* pc_seg_partial   = (const float*)d_in[2];
    const float* pc_seg_full      = (const float*)d_in[3];
    const float* pc_partial       = (const float*)d_in[4];
    const float* deformed         = (const float*)d_in[5];
    const float* p_rot            = (const float*)d_in[6];
    const float* p_t              = (const float*)d_in[7];
    const float* f_rot            = (const float*)d_in[8];
    const float* f_t              = (const float*)d_in[9];
    const float* tgt_rand_rot     = (const float*)d_in[10];
    const float* tgt_rand_t       = (const float*)d_in[11];
    const float* src_rand_rot     = (const float*)d_in[12];
    const float* src_rand_t       = (const float*)d_in[13];

    float* ws  = (float*)d_ws;
    float* out = (float*)d_out;

    init_ws_kernel<<<1, 256, 0, stream>>>(ws);

    cham_kernel<<<BS * 32, 256, 0, stream>>>(
        pc_partial, deformed, p_rot, p_t, f_rot, f_t,
        tgt_rand_rot, tgt_rand_t, src_rand_rot, src_rand_t,
        ws + OFF_CHAM);

    seg_kernel<<<BS * 8, 256, 0, stream>>>(pc_seg_partial, pc_seg_full, ws);

    loss_kernel<<<BS * 2, 256, 0, stream>>>(r_tokens_full, r_tokens_partial, ws);

    final_kernel<<<1, 1, 0, stream>>>(ws, out);
}

// Round 2
// 103.210 us; speedup vs baseline: 1.3065x; 1.3065x over previous
//
#include <hip/hip_runtime.h>
#include <math.h>

#define BS 16
#define NPTS 2048
#define MPTS 2048
#define KSEG 32
#define DDIM 128

// ws float layout
#define ACC_TOTAL 0
#define ACC_COUNT 1
#define OFF_XFORM 16                     // 16 batches * 12 floats = [16, 208)
#define OFF_SUPP 256                     // [256, 768)
#define OFF_SUPF 768                     // [768, 1280)
#define OFF_S2D  1280                    // [1280, 1792)
#define ZERO_REGION 2048
#define OFF_XN   2048                    // bs*N floats = [2048, 34816)
#define OFF_PART 34816                   // 8 sgroups * bs*N floats = 262144

__global__ __launch_bounds__(256) void init_ws_kernel(
    const float* __restrict__ p_rot, const float* __restrict__ p_t,
    const float* __restrict__ f_rot, const float* __restrict__ f_t,
    const float* __restrict__ tg_rot, const float* __restrict__ tg_t,
    const float* __restrict__ sr_rot, const float* __restrict__ sr_t,
    float* __restrict__ ws)
{
    // zero accumulator region, skipping the xform slots (written below by t<16)
    for (int i = threadIdx.x; i < ZERO_REGION; i += 256)
        if (i < OFF_XFORM || i >= OFF_XFORM + BS * 12) ws[i] = 0.0f;

    const int b = threadIdx.x;
    if (b < BS) {
        float P[9], F[9], Tg[9], Sr[9];
#pragma unroll
        for (int i = 0; i < 9; i++) {
            P[i] = p_rot[b*9+i];  F[i] = f_rot[b*9+i];
            Tg[i] = tg_rot[b*9+i]; Sr[i] = sr_rot[b*9+i];
        }
        float pt[3], ft[3], tt[3], st[3];
#pragma unroll
        for (int i = 0; i < 3; i++) {
            pt[i] = p_t[b*3+i]; ft[i] = f_t[b*3+i];
            tt[i] = tg_t[b*3+i]; st[i] = sr_t[b*3+i];
        }
        // row-vector convention: x = p @ R_total + t_total
        float A[9], Bm[9], R[9];
#pragma unroll
        for (int i = 0; i < 3; i++)
#pragma unroll
            for (int j = 0; j < 3; j++)
                A[i*3+j] = P[i*3+0]*Tg[j*3+0] + P[i*3+1]*Tg[j*3+1] + P[i*3+2]*Tg[j*3+2];
#pragma unroll
        for (int i = 0; i < 3; i++)
#pragma unroll
            for (int j = 0; j < 3; j++)
                Bm[i*3+j] = A[i*3+0]*Sr[0*3+j] + A[i*3+1]*Sr[1*3+j] + A[i*3+2]*Sr[2*3+j];
#pragma unroll
        for (int i = 0; i < 3; i++)
#pragma unroll
            for (int j = 0; j < 3; j++)
                R[i*3+j] = Bm[i*3+0]*F[j*3+0] + Bm[i*3+1]*F[j*3+1] + Bm[i*3+2]*F[j*3+2];
        float t0[3], t1[3], t2[3], t3[3], tv[3];
#pragma unroll
        for (int i = 0; i < 3; i++) t0[i] = pt[i] - tt[i];
#pragma unroll
        for (int j = 0; j < 3; j++)
            t1[j] = t0[0]*Tg[j*3+0] + t0[1]*Tg[j*3+1] + t0[2]*Tg[j*3+2];
#pragma unroll
        for (int j = 0; j < 3; j++)
            t2[j] = t1[0]*Sr[0*3+j] + t1[1]*Sr[1*3+j] + t1[2]*Sr[2*3+j];
#pragma unroll
        for (int i = 0; i < 3; i++) t3[i] = t2[i] + st[i] - ft[i];
#pragma unroll
        for (int j = 0; j < 3; j++)
            tv[j] = t3[0]*F[j*3+0] + t3[1]*F[j*3+1] + t3[2]*F[j*3+2];
        float* xf = ws + OFF_XFORM + b * 12;
#pragma unroll
        for (int i = 0; i < 9; i++) xf[i] = R[i];
#pragma unroll
        for (int i = 0; i < 3; i++) xf[9+i] = tv[i];
    }
}

// grid 512: b(16) x tile(4, 512 points each) x sg(8, 256 m each).
// Block = 4 waves; wave w scans m-slice [sg*256 + w*64, +64); each lane holds
// 8 points (p = 64j + lane). score = 0.5|y|^2 - x.y ; d2 = xn + 2*min(score).
__global__ __launch_bounds__(256) void cham_kernel(
    const float* __restrict__ pc_partial, const float* __restrict__ deformed,
    const float* __restrict__ ws_xf, float* __restrict__ xnArr,
    float* __restrict__ part)
{
    __shared__ float4 sh_y[256];     // 4 KB
    __shared__ float pmin[4][512];   // 8 KB

    const int bid  = blockIdx.x;
    const int b    = bid >> 5;
    const int r    = bid & 31;
    const int tile = r & 3;
    const int sg   = r >> 2;
    const int t = threadIdx.x;
    const int l = t & 63;
    const int w = t >> 6;

    // stage this block's 256-m slice as {y, 0.5*|y|^2}
    const float* def0 = deformed + (size_t)b * 3 * MPTS + sg * 256;
    {
        float y0 = def0[t], y1 = def0[MPTS + t], y2 = def0[2*MPTS + t];
        sh_y[t] = make_float4(y0, y1, y2, 0.5f*(y0*y0 + y1*y1 + y2*y2));
    }

    const float* xf = ws_xf + b * 12;
    const float R00=xf[0],R01=xf[1],R02=xf[2],
                R10=xf[3],R11=xf[4],R12=xf[5],
                R20=xf[6],R21=xf[7],R22=xf[8],
                T0=xf[9],T1=xf[10],T2=xf[11];

    float x0[8], x1[8], x2[8], mn[8];
    const int nbase = tile * 512 + l;
    const float* pcb = pc_partial + (size_t)b * NPTS * 3;
#pragma unroll
    for (int j = 0; j < 8; j++) {
        const float* pc = pcb + (size_t)(nbase + 64*j) * 3;
        float px = pc[0], py = pc[1], pz = pc[2];
        x0[j] = px*R00 + py*R10 + pz*R20 + T0;
        x1[j] = px*R01 + py*R11 + pz*R21 + T1;
        x2[j] = px*R02 + py*R12 + pz*R22 + T2;
        mn[j] = 3.402823466e+38f;
    }
    if (sg == 0 && w == 0) {
#pragma unroll
        for (int j = 0; j < 8; j++)
            xnArr[(size_t)b*NPTS + nbase + 64*j] =
                x0[j]*x0[j] + x1[j]*x1[j] + x2[j]*x2[j];
    }
    __syncthreads();

    const int mb = w * 64;
#pragma unroll 4
    for (int i = 0; i < 64; i++) {
        float4 y = sh_y[mb + i];                 // wave-uniform broadcast
#pragma unroll
        for (int j = 0; j < 8; j++) {
            float s = fmaf(-x2[j], y.z, fmaf(-x1[j], y.y, fmaf(-x0[j], y.x, y.w)));
            mn[j] = fminf(mn[j], s);
        }
    }

#pragma unroll
    for (int j = 0; j < 8; j++) pmin[w][64*j + l] = mn[j];
    __syncthreads();

    // reduce across 4 wave-slices; write coalesced [sg][b][n]
#pragma unroll
    for (int u = 0; u < 2; u++) {
        int p = t + 256 * u;
        float v = fminf(fminf(pmin[0][p], pmin[1][p]),
                        fminf(pmin[2][p], pmin[3][p]));
        part[(size_t)sg * (BS*NPTS) + (size_t)b * NPTS + tile*512 + p] = v;
    }
}

// grid: BS * 8; block finalizes cham for 256 n rows + segment sums, K=32.
__global__ __launch_bounds__(256) void seg_kernel(
    const float* __restrict__ seg_p, const float* __restrict__ seg_f,
    const float* __restrict__ xnArr, const float* __restrict__ part,
    float* __restrict__ ws)
{
    __shared__ float chamLDS[256];
    __shared__ float red[3][256];

    const int b = blockIdx.x >> 3;
    const int nc = blockIdx.x & 7;
    const int t = threadIdx.x;
    const int n0 = nc * 256;

    {
        const size_t nidx = (size_t)b * NPTS + n0 + t;
        float xn = xnArr[nidx];
        float pm = part[nidx];
#pragma unroll
        for (int sg = 1; sg < 8; sg++)
            pm = fminf(pm, part[(size_t)sg * (BS*NPTS) + nidx]);
        chamLDS[t] = fmaxf(fmaf(2.0f, pm, xn), 0.0f);
    }
    __syncthreads();

    const int k  = t & 31;
    const int ng = t >> 5;   // 8 n-groups
    const float* sp = seg_p + ((size_t)b * NPTS + n0) * KSEG;
    const float* sf = seg_f + ((size_t)b * NPTS + n0) * KSEG;

    float ap = 0.f, af = 0.f, a2 = 0.f;
#pragma unroll 4
    for (int i = 0; i < 32; i++) {
        int n = ng + 8 * i;
        float c  = chamLDS[n];
        float vp = sp[n * KSEG + k];
        float vf = sf[n * KSEG + k];
        ap += vp;
        a2 += vp * c;
        af += vf;
    }
    red[0][t] = ap; red[1][t] = af; red[2][t] = a2;
    __syncthreads();
    if (t < KSEG) {
        float s0 = 0.f, s1 = 0.f, s2 = 0.f;
#pragma unroll
        for (int g = 0; g < 8; g++) {
            s0 += red[0][g*32 + t];
            s1 += red[1][g*32 + t];
            s2 += red[2][g*32 + t];
        }
        atomicAdd(&ws[OFF_SUPP + b*KSEG + t], s0);
        atomicAdd(&ws[OFF_SUPF + b*KSEG + t], s1);
        atomicAdd(&ws[OFF_S2D  + b*KSEG + t], s2);
    }
}

// grid: BS*2 blocks; block handles 16 (b,k) cells, 16 threads per cell over D.
__global__ __launch_bounds__(256) void loss_kernel(
    const float* __restrict__ rf_tok, const float* __restrict__ rp_tok,
    float* __restrict__ ws)
{
    const int b  = blockIdx.x >> 1;
    const int kh = blockIdx.x & 1;
    const int t = threadIdx.x;
    const int cell = t >> 4;   // 0..15
    const int dg   = t & 15;
    const int k = kh * 16 + cell;

    const float supp = ws[OFF_SUPP + b*KSEG + k];
    const float supf = ws[OFF_SUPF + b*KSEG + k];
    const float s2d  = ws[OFF_S2D  + b*KSEG + k];
    const float spv = fmaxf(supp, 1.0f);
    const float sfv = fmaxf(supf, 1.0f);

    const float* rf = rf_tok + ((size_t)b * KSEG + k) * DDIM;
    const float* rp = rp_tok + ((size_t)b * KSEG + k) * DDIM;
    float acc = 0.f;
#pragma unroll
    for (int j = 0; j < 8; j++) {
        int d = dg + 16 * j;
        float v = rf[d] / sfv - rp[d] / spv;
        acc += v * v;
    }
#pragma unroll
    for (int off = 8; off; off >>= 1) acc += __shfl_xor(acc, off);

    __shared__ float lbuf[16], cbuf[16];
    if (dg == 0) {
        bool valid = (supp >= 20.0f) && (supf >= 20.0f);
        float arg = s2d / spv / 0.05f;
        float rel = 1.0f / (1.0f + expf(-arg));
        float ld = acc - rel; ld = ld * ld;
        bool msk = valid && (ld <= 20.0f);
        lbuf[cell] = msk ? ld : 0.0f;
        cbuf[cell] = msk ? 1.0f : 0.0f;
    }
    __syncthreads();
    if (t == 0) {
        float st = 0.f, sc = 0.f;
#pragma unroll
        for (int i = 0; i < 16; i++) { st += lbuf[i]; sc += cbuf[i]; }
        atomicAdd(&ws[ACC_TOTAL], st);
        atomicAdd(&ws[ACC_COUNT], sc);
    }
}

__global__ void final_kernel(const float* __restrict__ ws, float* __restrict__ out) {
    out[0] = ws[ACC_TOTAL] / (ws[ACC_COUNT] + 1.0f) * 1.0f;  // WEIGHT = 1.0
}

extern "C" void kernel_launch(void* const* d_in, const int* in_sizes, int n_in,
                              void* d_out, int out_size, void* d_ws, size_t ws_size,
                              hipStream_t stream) {
    const float* r_tokens_full    = (const float*)d_in[0];
    const float* r_tokens_partial = (const float*)d_in[1];
    const float* pc_seg_partial   = (const float*)d_in[2];
    const float* pc_seg_full      = (const float*)d_in[3];
    const float* pc_partial       = (const float*)d_in[4];
    const float* deformed         = (const float*)d_in[5];
    const float* p_rot            = (const float*)d_in[6];
    const float* p_t              = (const float*)d_in[7];
    const float* f_rot            = (const float*)d_in[8];
    const float* f_t              = (const float*)d_in[9];
    const float* tgt_rand_rot     = (const float*)d_in[10];
    const float* tgt_rand_t       = (const float*)d_in[11];
    const float* src_rand_rot     = (const float*)d_in[12];
    const float* src_rand_t       = (const float*)d_in[13];

    float* ws  = (float*)d_ws;
    float* out = (float*)d_out;

    init_ws_kernel<<<1, 256, 0, stream>>>(
        p_rot, p_t, f_rot, f_t, tgt_rand_rot, tgt_rand_t,
        src_rand_rot, src_rand_t, ws);

    cham_kernel<<<BS * 32, 256, 0, stream>>>(
        pc_partial, deformed, ws + OFF_XFORM, ws + OFF_XN, ws + OFF_PART);

    seg_kernel<<<BS * 8, 256, 0, stream>>>(
        pc_seg_partial, pc_seg_full, ws + OFF_XN, ws + OFF_PART, ws);

    loss_kernel<<<BS * 2, 256, 0, stream>>>(r_tokens_full, r_tokens_partial, ws);

    final_kernel<<<1, 1, 0, stream>>>(ws, out);
}

// Round 3
// 99.999 us; speedup vs baseline: 1.3484x; 1.0321x over previous
//
#include <hip/hip_runtime.h>
#include <math.h>

#define BS 16
#define NPTS 2048
#define MPTS 2048
#define KSEG 32
#define DDIM 128

// ws float layout (NO zero-init required: every word read is written earlier
// in the same call — the harness re-poisons ws to 0xAA before every launch)
#define OFF_XN    0                       // [0, 32768)            bs*N
#define OFF_PART  32768                   // [32768, 294912)       8 sg * bs*N
#define OFF_SEGP  294912                  // [294912, 307200)      3 * bs * 8 * 32
#define OFF_LOSSP 307200                  // [307200, 307264)      2 * 32

// grid 512: b(16) x tile(4, 512 points each) x sg(8, 256 m each).
// Block = 4 waves; wave w scans m-slice [sg*256 + w*64, +64); each lane holds
// 8 points (p = tile*512 + 64j + lane). score = 0.5|y|^2 - x.y ;
// d2 = xn + 2*min(score), finalized in seg_kernel.
__global__ __launch_bounds__(256) void cham_kernel(
    const float* __restrict__ pc_partial, const float* __restrict__ deformed,
    const float* __restrict__ p_rot, const float* __restrict__ p_t,
    const float* __restrict__ f_rot, const float* __restrict__ f_t,
    const float* __restrict__ tg_rot, const float* __restrict__ tg_t,
    const float* __restrict__ sr_rot, const float* __restrict__ sr_t,
    float* __restrict__ xnArr, float* __restrict__ part)
{
    __shared__ float4 sh_y[256];     // 4 KB
    __shared__ float pmin[4][512];   // 8 KB

    const int bid  = blockIdx.x;
    const int b    = bid >> 5;
    const int r    = bid & 31;
    const int tile = r & 3;
    const int sg   = r >> 2;
    const int t = threadIdx.x;
    const int l = t & 63;
    const int w = t >> 6;

    // stage this block's 256-m slice as {y, 0.5*|y|^2} (overlaps xform math)
    const float* def0 = deformed + (size_t)b * 3 * MPTS + sg * 256;
    {
        float y0 = def0[t], y1 = def0[MPTS + t], y2 = def0[2*MPTS + t];
        sh_y[t] = make_float4(y0, y1, y2, 0.5f*(y0*y0 + y1*y1 + y2*y2));
    }

    // fold the 5-transform chain into one affine (row-vector convention):
    // x = p @ R + T, R = ((P @ Tg^T) @ Sr) @ F^T,
    // T = (((p_t - tg_t) @ Tg^T) @ Sr + sr_t - f_t) @ F^T
    float R[9], T[3];
    {
        float P[9], F[9], Tg[9], Sr[9];
#pragma unroll
        for (int i = 0; i < 9; i++) {
            P[i] = p_rot[b*9+i];  F[i] = f_rot[b*9+i];
            Tg[i] = tg_rot[b*9+i]; Sr[i] = sr_rot[b*9+i];
        }
        float A[9], Bm[9];
#pragma unroll
        for (int i = 0; i < 3; i++)
#pragma unroll
            for (int j = 0; j < 3; j++)
                A[i*3+j] = P[i*3+0]*Tg[j*3+0] + P[i*3+1]*Tg[j*3+1] + P[i*3+2]*Tg[j*3+2];
#pragma unroll
        for (int i = 0; i < 3; i++)
#pragma unroll
            for (int j = 0; j < 3; j++)
                Bm[i*3+j] = A[i*3+0]*Sr[0*3+j] + A[i*3+1]*Sr[1*3+j] + A[i*3+2]*Sr[2*3+j];
#pragma unroll
        for (int i = 0; i < 3; i++)
#pragma unroll
            for (int j = 0; j < 3; j++)
                R[i*3+j] = Bm[i*3+0]*F[j*3+0] + Bm[i*3+1]*F[j*3+1] + Bm[i*3+2]*F[j*3+2];
        float t0[3], t1[3], t2[3], t3[3];
#pragma unroll
        for (int i = 0; i < 3; i++) t0[i] = p_t[b*3+i] - tg_t[b*3+i];
#pragma unroll
        for (int j = 0; j < 3; j++)
            t1[j] = t0[0]*Tg[j*3+0] + t0[1]*Tg[j*3+1] + t0[2]*Tg[j*3+2];
#pragma unroll
        for (int j = 0; j < 3; j++)
            t2[j] = t1[0]*Sr[0*3+j] + t1[1]*Sr[1*3+j] + t1[2]*Sr[2*3+j];
#pragma unroll
        for (int i = 0; i < 3; i++) t3[i] = t2[i] + sr_t[b*3+i] - f_t[b*3+i];
#pragma unroll
        for (int j = 0; j < 3; j++)
            T[j] = t3[0]*F[j*3+0] + t3[1]*F[j*3+1] + t3[2]*F[j*3+2];
    }

    float x0[8], x1[8], x2[8], mn[8];
    const int nbase = tile * 512 + l;
    const float* pcb = pc_partial + (size_t)b * NPTS * 3;
#pragma unroll
    for (int j = 0; j < 8; j++) {
        const float* pc = pcb + (size_t)(nbase + 64*j) * 3;
        float px = pc[0], py = pc[1], pz = pc[2];
        x0[j] = px*R[0] + py*R[3] + pz*R[6] + T[0];
        x1[j] = px*R[1] + py*R[4] + pz*R[7] + T[1];
        x2[j] = px*R[2] + py*R[5] + pz*R[8] + T[2];
        mn[j] = 3.402823466e+38f;
    }
    if (sg == 0 && w == 0) {
#pragma unroll
        for (int j = 0; j < 8; j++)
            xnArr[(size_t)b*NPTS + nbase + 64*j] =
                x0[j]*x0[j] + x1[j]*x1[j] + x2[j]*x2[j];
    }
    __syncthreads();

    const int mb = w * 64;
#pragma unroll 4
    for (int i = 0; i < 64; i++) {
        float4 y = sh_y[mb + i];                 // wave-uniform broadcast
#pragma unroll
        for (int j = 0; j < 8; j++) {
            float s = fmaf(-x2[j], y.z, fmaf(-x1[j], y.y, fmaf(-x0[j], y.x, y.w)));
            mn[j] = fminf(mn[j], s);
        }
    }

#pragma unroll
    for (int j = 0; j < 8; j++) pmin[w][64*j + l] = mn[j];
    __syncthreads();

    // reduce across 4 wave-slices; write coalesced [sg][b][n]
#pragma unroll
    for (int u = 0; u < 2; u++) {
        int p = t + 256 * u;
        float v = fminf(fminf(pmin[0][p], pmin[1][p]),
                        fminf(pmin[2][p], pmin[3][p]));
        part[(size_t)sg * (BS*NPTS) + (size_t)b * NPTS + tile*512 + p] = v;
    }
}

// grid: BS * 8; block (b,nc) finalizes cham for 256 n rows + per-block
// segment partial sums (no atomics). float4 loads: each wave-instr reads
// 8 consecutive rows x 128 B = 1 KB contiguous.
__global__ __launch_bounds__(256) void seg_kernel(
    const float* __restrict__ seg_p, const float* __restrict__ seg_f,
    const float* __restrict__ xnArr, const float* __restrict__ part,
    float* __restrict__ ws)
{
    __shared__ float chamLDS[256];
    __shared__ float red0[1024], red1[1024], red2[1024];  // 12 KB

    const int b = blockIdx.x >> 3;
    const int nc = blockIdx.x & 7;
    const int t = threadIdx.x;
    const int n0 = nc * 256;

    {
        const size_t nidx = (size_t)b * NPTS + n0 + t;
        float xn = xnArr[nidx];
        float pm = part[nidx];
#pragma unroll
        for (int sg = 1; sg < 8; sg++)
            pm = fminf(pm, part[(size_t)sg * (BS*NPTS) + nidx]);
        chamLDS[t] = fmaxf(fmaf(2.0f, pm, xn), 0.0f);
    }
    __syncthreads();

    // wave w covers rows [w*64, w*64+64): lane l -> rowoff=l>>3, k4=l&7
    const int l = t & 63;
    const int w = t >> 6;
    const int rowoff = l >> 3;
    const int k4 = l & 7;
    const float4* sp4 = (const float4*)(seg_p + ((size_t)b * NPTS + n0) * KSEG);
    const float4* sf4 = (const float4*)(seg_f + ((size_t)b * NPTS + n0) * KSEG);

    float4 ap = make_float4(0.f,0.f,0.f,0.f);
    float4 af = make_float4(0.f,0.f,0.f,0.f);
    float4 a2 = make_float4(0.f,0.f,0.f,0.f);
#pragma unroll
    for (int i = 0; i < 8; i++) {
        int n = w * 64 + i * 8 + rowoff;
        float c = chamLDS[n];                    // 8-lane broadcast, no conflicts
        float4 vp = sp4[n * 8 + k4];
        float4 vf = sf4[n * 8 + k4];
        ap.x += vp.x; ap.y += vp.y; ap.z += vp.z; ap.w += vp.w;
        af.x += vf.x; af.y += vf.y; af.z += vf.z; af.w += vf.w;
        a2.x = fmaf(vp.x, c, a2.x); a2.y = fmaf(vp.y, c, a2.y);
        a2.z = fmaf(vp.z, c, a2.z); a2.w = fmaf(vp.w, c, a2.w);
    }
    // store so that red[j*32 + k] (j = w*8+rowoff) is the partial for segment k
    red0[t*4+0] = ap.x; red0[t*4+1] = ap.y; red0[t*4+2] = ap.z; red0[t*4+3] = ap.w;
    red1[t*4+0] = af.x; red1[t*4+1] = af.y; red1[t*4+2] = af.z; red1[t*4+3] = af.w;
    red2[t*4+0] = a2.x; red2[t*4+1] = a2.y; red2[t*4+2] = a2.z; red2[t*4+3] = a2.w;
    __syncthreads();

    if (t < KSEG) {
        float s0 = 0.f, s1 = 0.f, s2 = 0.f;
#pragma unroll
        for (int j = 0; j < 32; j++) {
            s0 += red0[j*32 + t];
            s1 += red1[j*32 + t];
            s2 += red2[j*32 + t];
        }
        // segpart[x][b][nc][k]
        ws[OFF_SEGP + ((0*BS + b)*8 + nc)*KSEG + t] = s0;
        ws[OFF_SEGP + ((1*BS + b)*8 + nc)*KSEG + t] = s1;
        ws[OFF_SEGP + ((2*BS + b)*8 + nc)*KSEG + t] = s2;
    }
}

// grid: BS*2 blocks; block handles 16 (b,k) cells, 16 threads per cell over D.
// Writes per-block (total, count) partials — no atomics.
__global__ __launch_bounds__(256) void loss_kernel(
    const float* __restrict__ rf_tok, const float* __restrict__ rp_tok,
    float* __restrict__ ws)
{
    const int b  = blockIdx.x >> 1;
    const int kh = blockIdx.x & 1;
    const int t = threadIdx.x;
    const int cell = t >> 4;   // 0..15
    const int dg   = t & 15;
    const int k = kh * 16 + cell;

    // sum the 8 per-nc partials (redundant across the 16 lanes of a cell:
    // same-address broadcast loads, L2-hot)
    float supp = 0.f, supf = 0.f;
#pragma unroll
    for (int nc = 0; nc < 8; nc++) {
        supp += ws[OFF_SEGP + ((0*BS + b)*8 + nc)*KSEG + k];
        supf += ws[OFF_SEGP + ((1*BS + b)*8 + nc)*KSEG + k];
    }
    const float spv = fmaxf(supp, 1.0f);
    const float sfv = fmaxf(supf, 1.0f);

    const float* rf = rf_tok + ((size_t)b * KSEG + k) * DDIM;
    const float* rp = rp_tok + ((size_t)b * KSEG + k) * DDIM;
    float acc = 0.f;
#pragma unroll
    for (int j = 0; j < 8; j++) {
        int d = dg + 16 * j;
        float v = rf[d] / sfv - rp[d] / spv;
        acc += v * v;
    }
#pragma unroll
    for (int off = 8; off; off >>= 1) acc += __shfl_xor(acc, off);

    __shared__ float lbuf[16], cbuf[16];
    if (dg == 0) {
        float s2d = 0.f;
#pragma unroll
        for (int nc = 0; nc < 8; nc++)
            s2d += ws[OFF_SEGP + ((2*BS + b)*8 + nc)*KSEG + k];
        bool valid = (supp >= 20.0f) && (supf >= 20.0f);
        float arg = s2d / spv / 0.05f;
        float rel = 1.0f / (1.0f + expf(-arg));
        float ld = acc - rel; ld = ld * ld;
        bool msk = valid && (ld <= 20.0f);
        lbuf[cell] = msk ? ld : 0.0f;
        cbuf[cell] = msk ? 1.0f : 0.0f;
    }
    __syncthreads();
    if (t == 0) {
        float st = 0.f, sc = 0.f;
#pragma unroll
        for (int i = 0; i < 16; i++) { st += lbuf[i]; sc += cbuf[i]; }
        ws[OFF_LOSSP + blockIdx.x]      = st;
        ws[OFF_LOSSP + 32 + blockIdx.x] = sc;
    }
}

// one wave: sum 32 total-partials and 32 count-partials, write scalar out.
__global__ __launch_bounds__(64) void final_kernel(
    const float* __restrict__ ws, float* __restrict__ out)
{
    const int t = threadIdx.x;
    float v1 = (t < 32) ? ws[OFF_LOSSP + t] : 0.0f;
    float v2 = (t < 32) ? ws[OFF_LOSSP + 32 + t] : 0.0f;
#pragma unroll
    for (int off = 16; off; off >>= 1) {
        v1 += __shfl_xor(v1, off);
        v2 += __shfl_xor(v2, off);
    }
    if (t == 0) out[0] = v1 / (v2 + 1.0f) * 1.0f;  // WEIGHT = 1.0
}

extern "C" void kernel_launch(void* const* d_in, const int* in_sizes, int n_in,
                              void* d_out, int out_size, void* d_ws, size_t ws_size,
                              hipStream_t stream) {
    const float* r_tokens_full    = (const float*)d_in[0];
    const float* r_tokens_partial = (const float*)d_in[1];
    const float* pc_seg_partial   = (const float*)d_in[2];
    const float* pc_seg_full      = (const float*)d_in[3];
    const float* pc_partial       = (const float*)d_in[4];
    const float* deformed         = (const float*)d_in[5];
    const float* p_rot            = (const float*)d_in[6];
    const float* p_t              = (const float*)d_in[7];
    const float* f_rot            = (const float*)d_in[8];
    const float* f_t              = (const float*)d_in[9];
    const float* tgt_rand_rot     = (const float*)d_in[10];
    const float* tgt_rand_t       = (const float*)d_in[11];
    const float* src_rand_rot     = (const float*)d_in[12];
    const float* src_rand_t       = (const float*)d_in[13];

    float* ws  = (float*)d_ws;
    float* out = (float*)d_out;

    cham_kernel<<<BS * 32, 256, 0, stream>>>(
        pc_partial, deformed, p_rot, p_t, f_rot, f_t,
        tgt_rand_rot, tgt_rand_t, src_rand_rot, src_rand_t,
        ws + OFF_XN, ws + OFF_PART);

    seg_kernel<<<BS * 8, 256, 0, stream>>>(
        pc_seg_partial, pc_seg_full, ws + OFF_XN, ws + OFF_PART, ws);

    loss_kernel<<<BS * 2, 256, 0, stream>>>(r_tokens_full, r_tokens_partial, ws);

    final_kernel<<<1, 64, 0, stream>>>(ws, out);
}